// Round 1
// baseline (2616.120 us; speedup 1.0000x reference)
//
#include <hip/hip_runtime.h>
#include <hip/hip_bf16.h>
#include <stdint.h>

namespace {

constexpr int kDim   = 384;
constexpr int kHeads = 12;
constexpr int kHd    = 32;
constexpr int kN     = 343;     // window tokens (7^3)
constexpr int kTok   = 21952;   // B*NW*N = 8*8*343
constexpr long kPlane = (long)kTok * kDim;  // 8429568

__device__ __forceinline__ int regionOf(int c) { return c < 7 ? 0 : (c < 11 ? 1 : 2); }

// window-token index -> original flat row (same map for gather at qkv and scatter at LN1)
__device__ __forceinline__ int winRowMap(int wtok) {
  int w = wtok / kN, nn = wtok % kN;
  int bb = w >> 3, nwi = w & 7;
  int nz = nn / 49, nh = (nn / 7) % 7, nw = nn % 7;
  int uz = (((nwi >> 2) & 1) * 7 + nz + 3) % 14;
  int uh = (((nwi >> 1) & 1) * 7 + nh + 3) % 14;
  int uw = (((nwi     ) & 1) * 7 + nw + 3) % 14;
  return bb * 2744 + uz * 196 + uh * 14 + uw;
}

__device__ __forceinline__ float cpbFeat(int i) {
  float v = (float)(i - 6) * (8.0f / 6.0f);
  float a = log2f(fabsf(v) + 1.0f) * (1.0f / 3.0f);
  return v < 0.0f ? -a : a;
}

// ---- CPB MLP: tbl[2197][12] = relu(feat @ w1.T + b1) @ w2.T ----
__global__ __launch_bounds__(256) void cpb_table_kernel(
    const float* __restrict__ w1, const float* __restrict__ b1,
    const float* __restrict__ w2, float* __restrict__ tbl) {
  int t = blockIdx.x * 256 + threadIdx.x;
  if (t >= 2197 * kHeads) return;
  int row = t / kHeads, h = t - (t / kHeads) * kHeads;
  float f0 = cpbFeat(row / 169), f1 = cpbFeat((row / 13) % 13), f2 = cpbFeat(row % 13);
  float acc = 0.f;
  for (int j = 0; j < 512; ++j) {
    float hid = fmaf(f0, w1[j * 3 + 0], fmaf(f1, w1[j * 3 + 1], fmaf(f2, w1[j * 3 + 2], b1[j])));
    hid = fmaxf(hid, 0.f);
    acc = fmaf(hid, w2[h * 512 + j], acc);
  }
  tbl[row * kHeads + h] = acc;
}

// ---- bias[h][i][j] = 16*sigmoid(tbl[rel_idx(i,j)][h]) ----
__global__ __launch_bounds__(256) void cpb_bias_kernel(
    const float* __restrict__ tbl, float* __restrict__ bias) {
  int e = blockIdx.x * 256 + threadIdx.x;
  if (e >= kN * kN) return;
  int i = e / kN, j = e - (e / kN) * kN;
  int iz = i / 49, ih = (i / 7) % 7, iw = i % 7;
  int jz = j / 49, jh = (j / 7) % 7, jw = j % 7;
  int idx = (iz - jz + 6) * 169 + (ih - jh + 6) * 13 + (iw - jw + 6);
  #pragma unroll
  for (int h = 0; h < kHeads; ++h) {
    float v = tbl[idx * kHeads + h];
    bias[(h * kN + i) * kN + j] = 16.f / (1.f + __expf(-v));
  }
}

// ---- generic fp32 GEMM: out[M][N] = A[M][K] @ W[N][K]^T (+epilogue) ----
// MODE 0: A rows gathered via winRowMap; scatter to q/k/v [w][h][n][hd] with q/v bias
// MODE 1: out += bias[n]
// MODE 2: out = gelu_exact(out + bias[n])
template <int MODE>
__global__ __launch_bounds__(256) void gemm_kernel(
    const float* __restrict__ A, const float* __restrict__ W,
    const float* __restrict__ b0, const float* __restrict__ b1,
    float* __restrict__ out, int K, int N) {
  __shared__ __align__(16) float As[16][68];
  __shared__ __align__(16) float Bs[16][136];
  const int tid = threadIdx.x;
  const int tx = tid & 15, ty = tid >> 4;
  const int m0 = blockIdx.y * 64, n0 = blockIdx.x * 128;

  const int la_m = tid >> 2, la_k = (tid & 3) << 2;
  long arow = (MODE == 0) ? (long)winRowMap(m0 + la_m) : (long)(m0 + la_m);
  const float* Ap = A + arow * K + la_k;
  const int lb_n = tid >> 1, lb_k = (tid & 1) << 3;
  const float* Wp = W + (long)(n0 + lb_n) * K + lb_k;

  float acc[4][8];
  #pragma unroll
  for (int i = 0; i < 4; ++i)
    #pragma unroll
    for (int j = 0; j < 8; ++j) acc[i][j] = 0.f;

  for (int kt = 0; kt < K; kt += 16) {
    float4 av  = *(const float4*)(Ap + kt);
    float4 bv0 = *(const float4*)(Wp + kt);
    float4 bv1 = *(const float4*)(Wp + kt + 4);
    __syncthreads();
    As[la_k + 0][la_m] = av.x;  As[la_k + 1][la_m] = av.y;
    As[la_k + 2][la_m] = av.z;  As[la_k + 3][la_m] = av.w;
    Bs[lb_k + 0][lb_n] = bv0.x; Bs[lb_k + 1][lb_n] = bv0.y;
    Bs[lb_k + 2][lb_n] = bv0.z; Bs[lb_k + 3][lb_n] = bv0.w;
    Bs[lb_k + 4][lb_n] = bv1.x; Bs[lb_k + 5][lb_n] = bv1.y;
    Bs[lb_k + 6][lb_n] = bv1.z; Bs[lb_k + 7][lb_n] = bv1.w;
    __syncthreads();
    #pragma unroll
    for (int k = 0; k < 16; ++k) {
      float a[4], b[8];
      *(float4*)a     = *(const float4*)&As[k][ty << 2];
      *(float4*)&b[0] = *(const float4*)&Bs[k][tx << 3];
      *(float4*)&b[4] = *(const float4*)&Bs[k][(tx << 3) + 4];
      #pragma unroll
      for (int i = 0; i < 4; ++i)
        #pragma unroll
        for (int j = 0; j < 8; ++j) acc[i][j] = fmaf(a[i], b[j], acc[i][j]);
    }
  }

  if (MODE == 0) {
    // columns: [3][12][32]; 8 consecutive cols never cross a 32-group
    int nb = n0 + (tx << 3);
    int which = nb / 384;
    int rem = nb - which * 384;
    int h = rem >> 5, hd = rem & 31;
    const float* bp = (which == 0) ? b0 : ((which == 2) ? b1 : nullptr);
    float badd[8];
    #pragma unroll
    for (int j = 0; j < 8; ++j) badd[j] = bp ? bp[rem + j] : 0.f;
    #pragma unroll
    for (int i = 0; i < 4; ++i) {
      int mg = m0 + (ty << 2) + i;
      int w = mg / kN, nn = mg - (mg / kN) * kN;
      float* dst = out + (long)which * kPlane +
                   ((long)((w * kHeads + h) * kN + nn) << 5) + hd;
      float v[8];
      #pragma unroll
      for (int j = 0; j < 8; ++j) v[j] = acc[i][j] + badd[j];
      *(float4*)dst       = *(float4*)&v[0];
      *(float4*)(dst + 4) = *(float4*)&v[4];
    }
  } else {
    int nb = n0 + (tx << 3);
    float bb[8];
    #pragma unroll
    for (int j = 0; j < 8; ++j) bb[j] = b0[nb + j];
    #pragma unroll
    for (int i = 0; i < 4; ++i) {
      long mg = m0 + (ty << 2) + i;
      float v[8];
      #pragma unroll
      for (int j = 0; j < 8; ++j) {
        float t = acc[i][j] + bb[j];
        if (MODE == 2) t = 0.5f * t * (1.f + erff(t * 0.70710678118f));
        v[j] = t;
      }
      float* dst = out + mg * N + nb;
      *(float4*)dst       = *(float4*)&v[0];
      *(float4*)(dst + 4) = *(float4*)&v[4];
    }
  }
}

// ---- fused window attention: one block per (window, head), 8 waves ----
__global__ __launch_bounds__(512) void attn_kernel(
    const float* __restrict__ qb, const float* __restrict__ kb,
    const float* __restrict__ vb, const float* __restrict__ bias,
    const float* __restrict__ ls, float* __restrict__ out) {
  __shared__ __hip_bfloat16 Ksh[kN][34];
  __shared__ __hip_bfloat16 Vsh[kN][34];
  __shared__ float kinv[kN];
  __shared__ float cntf[kN];
  __shared__ float ps[8][344];

  const int wh = blockIdx.x;          // 0..767
  const int w = wh / kHeads, h = wh - (wh / kHeads) * kHeads;
  const int nwi = w & 7;
  const int tid = threadIdx.x, lane = tid & 63, wid = tid >> 6;

  const float* kp = kb + (long)wh * kN * kHd;
  const float* vp = vb + (long)wh * kN * kHd;
  for (int idx = tid; idx < kN * kHd; idx += 512) {
    int r = idx >> 5, c = idx & 31;
    Ksh[r][c] = __float2bfloat16(kp[idx]);
    Vsh[r][c] = __float2bfloat16(vp[idx]);
  }
  __syncthreads();
  if (tid < kN) {
    float s = 0.f;
    #pragma unroll
    for (int c = 0; c < kHd; ++c) {
      float f = __bfloat162float(Ksh[tid][c]);
      s = fmaf(f, f, s);
    }
    kinv[tid] = 1.f / fmaxf(sqrtf(s), 1e-12f);
    int jz = tid / 49, jh = (tid / 7) % 7, jw = tid % 7;
    int gz = ((nwi >> 2) & 1) * 7 + jz;
    int gh = ((nwi >> 1) & 1) * 7 + jh;
    int gw = ((nwi     ) & 1) * 7 + jw;
    cntf[tid] = (float)(regionOf(gz) * 9 + regionOf(gh) * 3 + regionOf(gw));
  }
  __syncthreads();
  const float scale = __expf(fminf(ls[h], 4.6051702f));  // exp(min(ls, ln 100))

  for (int i = wid; i < kN; i += 8) {
    const float* qp = qb + ((long)wh * kN + i) * kHd;
    float qr[kHd];
    float qs = 0.f;
    #pragma unroll
    for (int c = 0; c < kHd; ++c) { qr[c] = qp[c]; qs = fmaf(qr[c], qr[c], qs); }
    float qmul = scale / fmaxf(sqrtf(qs), 1e-12f);
    #pragma unroll
    for (int c = 0; c < kHd; ++c) qr[c] *= qmul;
    float cnt_i = cntf[i];
    const float* bp = bias + (long)(h * kN + i) * kN;

    float sv[6];
    #pragma unroll
    for (int t = 0; t < 6; ++t) {
      int j = lane + t * 64;
      if (j < kN) {
        const unsigned int* Ku = (const unsigned int*)&Ksh[j][0];
        float dot = 0.f;
        #pragma unroll
        for (int c2 = 0; c2 < 16; ++c2) {
          unsigned int u = Ku[c2];
          float f0 = __uint_as_float(u << 16);
          float f1 = __uint_as_float(u & 0xffff0000u);
          dot = fmaf(qr[2 * c2], f0, dot);
          dot = fmaf(qr[2 * c2 + 1], f1, dot);
        }
        sv[t] = dot * kinv[j] + bp[j] + ((cntf[j] != cnt_i) ? -100.f : 0.f);
      } else {
        sv[t] = -3e38f;
      }
    }
    float m = fmaxf(fmaxf(fmaxf(sv[0], sv[1]), fmaxf(sv[2], sv[3])), fmaxf(sv[4], sv[5]));
    #pragma unroll
    for (int o = 32; o; o >>= 1) m = fmaxf(m, __shfl_xor(m, o));
    float lsum = 0.f;
    #pragma unroll
    for (int t = 0; t < 6; ++t) {
      int j = lane + t * 64;
      float p = (j < kN) ? __expf(sv[t] - m) : 0.f;
      if (j < kN) ps[wid][j] = p;
      lsum += p;
    }
    #pragma unroll
    for (int o = 32; o; o >>= 1) lsum += __shfl_xor(lsum, o);
    float rinv = 1.f / lsum;
    asm volatile("s_waitcnt lgkmcnt(0)" ::: "memory");  // wave-local ps visible

    int half = lane >> 5, c = lane & 31;
    int j0 = half ? 172 : 0, j1 = half ? kN : 172;
    float acc = 0.f;
    for (int j = j0; j < j1; ++j)
      acc = fmaf(ps[wid][j], __bfloat162float(Vsh[j][c]), acc);
    acc += __shfl_xor(acc, 32);
    if (half == 0)
      out[((long)(w * kN + i)) * kDim + h * kHd + c] = acc * rinv;
  }
}

// ---- LayerNorm + residual (one wave per token row) ----
// GATHER=1: src row = window-token order, dst = winRowMap(row) (LN1 after proj)
// GATHER=0: src/dst = row (LN2)
template <int GATHER>
__global__ __launch_bounds__(64) void ln_kernel(
    const float* __restrict__ src, const float* __restrict__ resid,
    const float* __restrict__ g, const float* __restrict__ b,
    float* __restrict__ out) {
  int row = blockIdx.x, lane = threadIdx.x;
  long dst = GATHER ? (long)winRowMap(row) : (long)row;
  float t[6];
  float sum = 0.f, sq = 0.f;
  #pragma unroll
  for (int i = 0; i < 6; ++i) {
    t[i] = src[(long)row * kDim + i * 64 + lane];
    sum += t[i];
    sq = fmaf(t[i], t[i], sq);
  }
  #pragma unroll
  for (int o = 32; o; o >>= 1) { sum += __shfl_xor(sum, o); sq += __shfl_xor(sq, o); }
  float mean = sum * (1.f / kDim);
  float var = sq * (1.f / kDim) - mean * mean;
  float rs = rsqrtf(var + 1e-5f);
  #pragma unroll
  for (int i = 0; i < 6; ++i) {
    int c = i * 64 + lane;
    out[dst * kDim + c] = resid[dst * kDim + c] + (t[i] - mean) * rs * g[c] + b[c];
  }
}

}  // namespace

extern "C" void kernel_launch(void* const* d_in, const int* in_sizes, int n_in,
                              void* d_out, int out_size, void* d_ws, size_t ws_size,
                              hipStream_t stream) {
  const float* x      = (const float*)d_in[0];
  const float* qkv_w  = (const float*)d_in[1];
  const float* q_bias = (const float*)d_in[2];
  const float* v_bias = (const float*)d_in[3];
  const float* lscale = (const float*)d_in[4];
  const float* cpb_w1 = (const float*)d_in[5];
  const float* cpb_b1 = (const float*)d_in[6];
  const float* cpb_w2 = (const float*)d_in[7];
  const float* proj_w = (const float*)d_in[8];
  const float* proj_b = (const float*)d_in[9];
  const float* n1g    = (const float*)d_in[10];
  const float* n1b    = (const float*)d_in[11];
  const float* n2g    = (const float*)d_in[12];
  const float* n2b    = (const float*)d_in[13];
  const float* fc1_w  = (const float*)d_in[14];
  const float* fc1_b  = (const float*)d_in[15];
  const float* fc2_w  = (const float*)d_in[16];
  const float* fc2_b  = (const float*)d_in[17];
  float* outp = (float*)d_out;
  float* ws = (float*)d_ws;

  // workspace layout (floats); total 52,015,616 floats = ~198.4 MiB
  float* tbl2  = ws;                 //      26,364
  float* biasb = ws + 26368;         //   1,411,788
  float* qkv   = ws + 1438208;       //  25,288,704 (q,k,v planes)
  float* attno = ws + 26726912;      //   8,429,568
  float* projt = ws + 35156480;      //   8,429,568
  float* x1    = ws + 43586048;      //   8,429,568
  float* hbuf  = qkv;                //  33,718,272 (overlays qkv+attno, free by then)
  float* h2    = projt;              //  overlays projt (free after LN1)

  cpb_table_kernel<<<103, 256, 0, stream>>>(cpb_w1, cpb_b1, cpb_w2, tbl2);
  cpb_bias_kernel<<<460, 256, 0, stream>>>(tbl2, biasb);

  // qkv: [21952,384](gathered) @ [384,1152]^T -> q/k/v [w][h][n][hd]
  gemm_kernel<0><<<dim3(9, 343), 256, 0, stream>>>(x, qkv_w, q_bias, v_bias, qkv, 384, 1152);

  attn_kernel<<<768, 512, 0, stream>>>(qkv, qkv + kPlane, qkv + 2 * kPlane,
                                       biasb, lscale, attno);

  // proj: [21952,384] @ [384,384]^T + b
  gemm_kernel<1><<<dim3(3, 343), 256, 0, stream>>>(attno, proj_w, proj_b, nullptr, projt, 384, 384);

  // x1 = x + LN(win_rev(proj))  (scatter to original order)
  ln_kernel<1><<<21952, 64, 0, stream>>>(projt, x, n1g, n1b, x1);

  // fc1 + gelu: [21952,384] @ [384,1536]^T
  gemm_kernel<2><<<dim3(12, 343), 256, 0, stream>>>(x1, fc1_w, fc1_b, nullptr, hbuf, 384, 1536);

  // fc2: [21952,1536] @ [1536,384]^T
  gemm_kernel<1><<<dim3(3, 343), 256, 0, stream>>>(hbuf, fc2_w, fc2_b, nullptr, h2, 1536, 384);

  // out = x1 + LN(h2)
  ln_kernel<0><<<21952, 64, 0, stream>>>(h2, x1, n2g, n2b, outp);
}

// Round 2
// 360.810 us; speedup vs baseline: 7.2507x; 7.2507x over previous
//
#include <hip/hip_runtime.h>
#include <hip/hip_bf16.h>
#include <stdint.h>

namespace {

typedef __attribute__((ext_vector_type(8))) short s8v;
typedef __attribute__((ext_vector_type(4))) float f4v;
typedef __attribute__((ext_vector_type(8))) unsigned short us8;

constexpr int kN    = 343;     // window tokens (7^3)
constexpr size_t kPlaneE = 768ull * 343 * 32;  // 8,429,568 elems per q/k/v plane

__device__ __forceinline__ int regionOf(int c) { return c < 7 ? 0 : (c < 11 ? 1 : 2); }

__device__ __forceinline__ int winRowMap(int wtok) {
  int w = wtok / kN, nn = wtok % kN;
  int bb = w >> 3, nwi = w & 7;
  int nz = nn / 49, nh = (nn / 7) % 7, nw = nn % 7;
  int uz = (((nwi >> 2) & 1) * 7 + nz + 3) % 14;
  int uh = (((nwi >> 1) & 1) * 7 + nh + 3) % 14;
  int uw = (((nwi     ) & 1) * 7 + nw + 3) % 14;
  return bb * 2744 + uz * 196 + uh * 14 + uw;
}

__device__ __forceinline__ unsigned short f2bf(float f) {
  union { float f; unsigned u; } a; a.f = f;
  unsigned r = a.u + 0x7fffu + ((a.u >> 16) & 1u);
  return (unsigned short)(r >> 16);
}
__device__ __forceinline__ float bf2f(unsigned short u) {
  union { unsigned u; float f; } a; a.u = ((unsigned)u) << 16; return a.f;
}

__device__ __forceinline__ void gload16(const void* g, void* l) {
  __builtin_amdgcn_global_load_lds(
      (const __attribute__((address_space(1))) unsigned int*)g,
      (__attribute__((address_space(3))) unsigned int*)l, 16, 0, 0);
}

__device__ __forceinline__ float cpbFeat(int i) {
  float v = (float)(i - 6) * (8.0f / 6.0f);
  float a = log2f(fabsf(v) + 1.0f) * (1.0f / 3.0f);
  return v < 0.0f ? -a : a;
}

// ---- fp32 -> bf16 conversion (weights / activations), n8 = count/8 ----
__global__ __launch_bounds__(256) void cvt_bf16_kernel(
    const float* __restrict__ src, unsigned short* __restrict__ dst, int n8) {
  int i = blockIdx.x * 256 + threadIdx.x;
  if (i >= n8) return;
  const float* s = src + (size_t)i * 8;
  float4 a = *(const float4*)s;
  float4 b = *(const float4*)(s + 4);
  us8 o;
  o[0]=f2bf(a.x); o[1]=f2bf(a.y); o[2]=f2bf(a.z); o[3]=f2bf(a.w);
  o[4]=f2bf(b.x); o[5]=f2bf(b.y); o[6]=f2bf(b.z); o[7]=f2bf(b.w);
  *(us8*)(dst + (size_t)i * 8) = o;
}

// ---- gather x into window order + convert to bf16 ----
__global__ __launch_bounds__(256) void gather_x_kernel(
    const float* __restrict__ x, unsigned short* __restrict__ xg) {
  int chunk = blockIdx.x * 256 + threadIdx.x;
  if (chunk >= 21952 * 48) return;
  int wtok = chunk / 48, c = (chunk - wtok * 48) * 8;
  long row = winRowMap(wtok);
  const float* s = x + row * 384 + c;
  float4 a = *(const float4*)s;
  float4 b = *(const float4*)(s + 4);
  us8 o;
  o[0]=f2bf(a.x); o[1]=f2bf(a.y); o[2]=f2bf(a.z); o[3]=f2bf(a.w);
  o[4]=f2bf(b.x); o[5]=f2bf(b.y); o[6]=f2bf(b.z); o[7]=f2bf(b.w);
  *(us8*)(xg + (size_t)wtok * 384 + c) = o;
}

// ---- CPB MLP: tbl[2197][12] ----
__global__ __launch_bounds__(256) void cpb_table_kernel(
    const float* __restrict__ w1, const float* __restrict__ b1,
    const float* __restrict__ w2, float* __restrict__ tbl) {
  int t = blockIdx.x * 256 + threadIdx.x;
  if (t >= 2197 * 12) return;
  int row = t / 12, h = t - (t / 12) * 12;
  float f0 = cpbFeat(row / 169), f1 = cpbFeat((row / 13) % 13), f2 = cpbFeat(row % 13);
  float acc = 0.f;
  for (int j = 0; j < 512; ++j) {
    float hid = fmaf(f0, w1[j*3+0], fmaf(f1, w1[j*3+1], fmaf(f2, w1[j*3+2], b1[j])));
    hid = fmaxf(hid, 0.f);
    acc = fmaf(hid, w2[h*512 + j], acc);
  }
  tbl[row * 12 + h] = acc;
}

// ---- bias in MFMA C-fragment layout: biasf[h][it][jt][lane][reg] fp32 ----
__global__ __launch_bounds__(256) void cpb_bias_frag_kernel(
    const float* __restrict__ tbl, float* __restrict__ biasf) {
  int gid = blockIdx.x * 256 + threadIdx.x;
  if (gid >= 12 * 22 * 22 * 64) return;
  int lane = gid & 63, tile = gid >> 6;
  int jt = tile % 22, it = (tile / 22) % 22, h = tile / 484;
  int j = jt * 16 + (lane & 15);
  float v[4];
  #pragma unroll
  for (int r = 0; r < 4; ++r) {
    int i = it * 16 + (lane >> 4) * 4 + r;
    float val = -30000.f;
    if (i < kN && j < kN) {
      int iz = i/49, ih = (i/7)%7, iw = i%7;
      int jz = j/49, jh = (j/7)%7, jw = j%7;
      int idx = (iz-jz+6)*169 + (ih-jh+6)*13 + (iw-jw+6);
      float tv = tbl[idx*12 + h];
      val = 16.f / (1.f + __expf(-tv));
    }
    v[r] = val;
  }
  float4* dst = (float4*)(biasf + ((size_t)tile << 8) + (lane << 2));
  *dst = make_float4(v[0], v[1], v[2], v[3]);
}

// ---- bf16 MFMA GEMM: out[M][N] = A[M][K] @ W[N][K]^T, BM=64 BN=128 BK=32 ----
// MODE 0: qkv scatter to q/k/v planes bf16 (+q/v bias)
// MODE 1: +bias, fp32 out
// MODE 2: +bias, exact GELU, bf16 out
template <int MODE>
__global__ __launch_bounds__(256) void gemm_bf16(
    const unsigned short* __restrict__ A, const unsigned short* __restrict__ W,
    const float* __restrict__ b0, const float* __restrict__ b1,
    void* __restrict__ outv, int K, int N) {
  __shared__ __align__(16) unsigned short As[2][64][32];
  __shared__ __align__(16) unsigned short Bs[2][128][32];
  const int tid = threadIdx.x, lane = tid & 63, wid = tid >> 6;
  const int wr = wid >> 1, wc = wid & 1;
  const int lr = lane & 15, lc = lane >> 4;
  const int m0 = blockIdx.y * 64, n0 = blockIdx.x * 128;

  const int sr = lane >> 2, sc = (lane & 3) << 3;
  const unsigned short* ga  = A + (size_t)(m0 + wid * 16 + sr) * K + sc;
  const unsigned short* gb0 = W + (size_t)(n0 + wid * 32 + sr) * K + sc;
  const unsigned short* gb1 = gb0 + (size_t)16 * K;

  f4v acc[2][4];
  const f4v zero4 = {0.f, 0.f, 0.f, 0.f};
  #pragma unroll
  for (int i = 0; i < 2; ++i)
    #pragma unroll
    for (int j = 0; j < 4; ++j) acc[i][j] = zero4;

  const int nk = K >> 5;
  gload16(ga,  &As[0][wid*16][0]);
  gload16(gb0, &Bs[0][wid*32][0]);
  gload16(gb1, &Bs[0][wid*32 + 16][0]);
  __syncthreads();
  for (int kt = 0; kt < nk; ++kt) {
    int cur = kt & 1;
    if (kt + 1 < nk) {
      gload16(ga  + (kt+1)*32, &As[cur^1][wid*16][0]);
      gload16(gb0 + (kt+1)*32, &Bs[cur^1][wid*32][0]);
      gload16(gb1 + (kt+1)*32, &Bs[cur^1][wid*32 + 16][0]);
    }
    s8v af0 = *(const s8v*)&As[cur][wr*32 + lr][lc*8];
    s8v af1 = *(const s8v*)&As[cur][wr*32 + 16 + lr][lc*8];
    #pragma unroll
    for (int ni = 0; ni < 4; ++ni) {
      s8v bf = *(const s8v*)&Bs[cur][wc*64 + ni*16 + lr][lc*8];
      acc[0][ni] = __builtin_amdgcn_mfma_f32_16x16x32_bf16(af0, bf, acc[0][ni], 0, 0, 0);
      acc[1][ni] = __builtin_amdgcn_mfma_f32_16x16x32_bf16(af1, bf, acc[1][ni], 0, 0, 0);
    }
    __syncthreads();
  }

  if (MODE == 0) {
    unsigned short* qkv = (unsigned short*)outv;
    #pragma unroll
    for (int mi = 0; mi < 2; ++mi)
      #pragma unroll
      for (int ni = 0; ni < 4; ++ni) {
        int cg = n0 + wc*64 + ni*16 + lr;
        int which = cg / 384, rem = cg - which * 384;
        const float* bp = (which == 0) ? b0 : (which == 2 ? b1 : nullptr);
        float badd = bp ? bp[rem] : 0.f;
        unsigned short* plane = qkv + (size_t)which * kPlaneE;
        #pragma unroll
        for (int r = 0; r < 4; ++r) {
          int mg = m0 + wr*32 + mi*16 + lc*4 + r;
          int w = mg / kN, nn = mg - w * kN;
          plane[((size_t)(w * 12 + (rem >> 5)) * kN + nn) * 32 + (rem & 31)] =
              f2bf(acc[mi][ni][r] + badd);
        }
      }
  } else {
    #pragma unroll
    for (int mi = 0; mi < 2; ++mi)
      #pragma unroll
      for (int ni = 0; ni < 4; ++ni) {
        int cg = n0 + wc*64 + ni*16 + lr;
        float badd = b0[cg];
        #pragma unroll
        for (int r = 0; r < 4; ++r) {
          size_t mg = (size_t)(m0 + wr*32 + mi*16 + lc*4 + r);
          float t = acc[mi][ni][r] + badd;
          if (MODE == 2) {
            t = 0.5f * t * (1.f + erff(t * 0.70710678118f));
            ((unsigned short*)outv)[mg * N + cg] = f2bf(t);
          } else {
            ((float*)outv)[mg * N + cg] = t;
          }
        }
      }
  }
}

// ---- fused window attention, MFMA, one block per (window, head), 8 waves ----
__global__ __launch_bounds__(512) void attn_mfma(
    const unsigned short* __restrict__ qp, const unsigned short* __restrict__ kp,
    const unsigned short* __restrict__ vp, const float* __restrict__ biasf,
    const float* __restrict__ ls, unsigned short* __restrict__ outb) {
  __shared__ __align__(16) unsigned short Ksh[352][40];
  __shared__ __align__(16) unsigned short Vt[32][360];
  __shared__ __align__(16) unsigned short ps[8][16][360];
  __shared__ float qinvS[352], kinvS[352], cntS[352];

  const int wh = blockIdx.x;
  const int w = wh / 12, h = wh - w * 12;
  const int nwi = w & 7;
  const int tid = threadIdx.x, lane = tid & 63, wid = tid >> 6;
  const unsigned short* qb = qp + (size_t)wh * kN * 32;
  const unsigned short* kb = kp + (size_t)wh * kN * 32;
  const unsigned short* vb = vp + (size_t)wh * kN * 32;
  const float scale = __expf(fminf(ls[h], 4.6051702f));

  // stage K rows 0..351 (pad rows zero)
  for (int idx = tid; idx < 1408; idx += 512) {
    int r = idx >> 2, c8 = (idx & 3) << 3;
    us8 v = {0,0,0,0,0,0,0,0};
    if (r < kN) v = *(const us8*)(kb + r * 32 + c8);
    *(us8*)&Ksh[r][c8] = v;
  }
  // zero Vt pad cols 343..359
  for (int idx = tid; idx < 32 * 17; idx += 512) {
    int d = idx / 17, c = kN + (idx - (idx / 17) * 17);
    Vt[d][c] = 0;
  }
  // transpose V into Vt[32][360]
  for (int idx = tid; idx < 1372; idx += 512) {
    int r = idx >> 2, c8 = (idx & 3) << 3;
    us8 v = *(const us8*)(vb + r * 32 + c8);
    #pragma unroll
    for (int e = 0; e < 8; ++e) Vt[c8 + e][r] = v[e];
  }
  // norms + region counts
  for (int t = tid; t < 352; t += 512) {
    if (t < kN) {
      float qs = 0.f, ks = 0.f;
      #pragma unroll
      for (int c8 = 0; c8 < 4; ++c8) {
        us8 qv = *(const us8*)(qb + t * 32 + c8 * 8);
        us8 kv = *(const us8*)(kb + t * 32 + c8 * 8);
        #pragma unroll
        for (int e = 0; e < 8; ++e) {
          float f = bf2f(qv[e]); qs = fmaf(f, f, qs);
          float g = bf2f(kv[e]); ks = fmaf(g, g, ks);
        }
      }
      qinvS[t] = scale / fmaxf(sqrtf(qs), 1e-12f);
      kinvS[t] = 1.f / fmaxf(sqrtf(ks), 1e-12f);
      int jz = t / 49, jh = (t / 7) % 7, jw = t % 7;
      cntS[t] = (float)(regionOf(((nwi >> 2) & 1) * 7 + jz) * 9 +
                        regionOf(((nwi >> 1) & 1) * 7 + jh) * 3 +
                        regionOf(((nwi     ) & 1) * 7 + jw));
    } else {
      qinvS[t] = 1.f; kinvS[t] = 0.f; cntS[t] = 0.f;
    }
  }
  __syncthreads();

  const int lr = lane & 15, lc = lane >> 4;
  const f4v zero4 = {0.f, 0.f, 0.f, 0.f};

  for (int mt = wid; mt < 22; mt += 8) {
    const int i0 = mt * 16;
    s8v qa = *(const s8v*)(qb + (size_t)(i0 + lr) * 32 + lc * 8);
    float qi[4], ci[4];
    #pragma unroll
    for (int r = 0; r < 4; ++r) {
      qi[r] = qinvS[i0 + lc * 4 + r];
      ci[r] = cntS[i0 + lc * 4 + r];
    }
    float sreg[22][4];
    #pragma unroll
    for (int jt = 0; jt < 22; ++jt) {
      s8v kf = *(const s8v*)&Ksh[jt * 16 + lr][lc * 8];
      f4v s4 = __builtin_amdgcn_mfma_f32_16x16x32_bf16(qa, kf, zero4, 0, 0, 0);
      float kj = kinvS[jt * 16 + lr];
      float cj = cntS[jt * 16 + lr];
      float4 bq = *(const float4*)(biasf + (((size_t)(h * 22 + mt) * 22 + jt) << 8) + (lane << 2));
      sreg[jt][0] = s4[0] * qi[0] * kj + bq.x + ((cj != ci[0]) ? -100.f : 0.f);
      sreg[jt][1] = s4[1] * qi[1] * kj + bq.y + ((cj != ci[1]) ? -100.f : 0.f);
      sreg[jt][2] = s4[2] * qi[2] * kj + bq.z + ((cj != ci[2]) ? -100.f : 0.f);
      sreg[jt][3] = s4[3] * qi[3] * kj + bq.w + ((cj != ci[3]) ? -100.f : 0.f);
    }
    float mx[4] = {-3e38f, -3e38f, -3e38f, -3e38f};
    #pragma unroll
    for (int jt = 0; jt < 22; ++jt)
      #pragma unroll
      for (int r = 0; r < 4; ++r) mx[r] = fmaxf(mx[r], sreg[jt][r]);
    #pragma unroll
    for (int off = 1; off < 16; off <<= 1)
      #pragma unroll
      for (int r = 0; r < 4; ++r) mx[r] = fmaxf(mx[r], __shfl_xor(mx[r], off));
    float sum[4] = {0.f, 0.f, 0.f, 0.f};
    #pragma unroll
    for (int jt = 0; jt < 22; ++jt)
      #pragma unroll
      for (int r = 0; r < 4; ++r) {
        float p = __expf(sreg[jt][r] - mx[r]);
        sum[r] += p;
        ps[wid][lc * 4 + r][jt * 16 + lr] = f2bf(p);
      }
    #pragma unroll
    for (int off = 1; off < 16; off <<= 1)
      #pragma unroll
      for (int r = 0; r < 4; ++r) sum[r] += __shfl_xor(sum[r], off);
    float rinv[4];
    #pragma unroll
    for (int r = 0; r < 4; ++r) rinv[r] = 1.f / sum[r];

    f4v o0 = zero4, o1 = zero4;
    #pragma unroll
    for (int ks = 0; ks < 11; ++ks) {
      s8v pa = *(const s8v*)&ps[wid][lr][ks * 32 + lc * 8];
      s8v v0 = *(const s8v*)&Vt[lr][ks * 32 + lc * 8];
      s8v v1 = *(const s8v*)&Vt[16 + lr][ks * 32 + lc * 8];
      o0 = __builtin_amdgcn_mfma_f32_16x16x32_bf16(pa, v0, o0, 0, 0, 0);
      o1 = __builtin_amdgcn_mfma_f32_16x16x32_bf16(pa, v1, o1, 0, 0, 0);
    }
    #pragma unroll
    for (int r = 0; r < 4; ++r) {
      int i = i0 + lc * 4 + r;
      if (i < kN) {
        size_t base = ((size_t)(w * kN + i)) * 384 + h * 32;
        outb[base + lr]      = f2bf(o0[r] * rinv[r]);
        outb[base + 16 + lr] = f2bf(o1[r] * rinv[r]);
      }
    }
  }
}

// ---- LayerNorm + residual ----
template <int GATHER, int WBF>
__global__ __launch_bounds__(64) void ln_kernel(
    const float* __restrict__ src, const float* __restrict__ resid,
    const float* __restrict__ g, const float* __restrict__ b,
    float* __restrict__ out, unsigned short* __restrict__ outbf) {
  int row = blockIdx.x, lane = threadIdx.x;
  long dst = GATHER ? (long)winRowMap(row) : (long)row;
  float t[6];
  float sum = 0.f, sq = 0.f;
  #pragma unroll
  for (int i = 0; i < 6; ++i) {
    t[i] = src[(long)row * 384 + i * 64 + lane];
    sum += t[i];
    sq = fmaf(t[i], t[i], sq);
  }
  #pragma unroll
  for (int o = 32; o; o >>= 1) { sum += __shfl_xor(sum, o); sq += __shfl_xor(sq, o); }
  float mean = sum * (1.f / 384.f);
  float var = sq * (1.f / 384.f) - mean * mean;
  float rs = rsqrtf(var + 1e-5f);
  #pragma unroll
  for (int i = 0; i < 6; ++i) {
    int c = i * 64 + lane;
    float val = resid[dst * 384 + c] + (t[i] - mean) * rs * g[c] + b[c];
    out[dst * 384 + c] = val;
    if (WBF) outbf[dst * 384 + c] = f2bf(val);
  }
}

}  // namespace

extern "C" void kernel_launch(void* const* d_in, const int* in_sizes, int n_in,
                              void* d_out, int out_size, void* d_ws, size_t ws_size,
                              hipStream_t stream) {
  const float* x      = (const float*)d_in[0];
  const float* qkv_w  = (const float*)d_in[1];
  const float* q_bias = (const float*)d_in[2];
  const float* v_bias = (const float*)d_in[3];
  const float* lscale = (const float*)d_in[4];
  const float* cpb_w1 = (const float*)d_in[5];
  const float* cpb_b1 = (const float*)d_in[6];
  const float* cpb_w2 = (const float*)d_in[7];
  const float* proj_w = (const float*)d_in[8];
  const float* proj_b = (const float*)d_in[9];
  const float* n1g    = (const float*)d_in[10];
  const float* n1b    = (const float*)d_in[11];
  const float* n2g    = (const float*)d_in[12];
  const float* n2b    = (const float*)d_in[13];
  const float* fc1_w  = (const float*)d_in[14];
  const float* fc1_b  = (const float*)d_in[15];
  const float* fc2_w  = (const float*)d_in[16];
  const float* fc2_b  = (const float*)d_in[17];
  float* outp = (float*)d_out;
  char* wsb = (char*)d_ws;

  // workspace layout (bytes), total ~178 MB
  float*          biasf = (float*)(wsb + 0);                    //  5,947,392
  float*          tbl   = (float*)(wsb + 5947392);              //    105,456
  unsigned short* qkvp  = (unsigned short*)(wsb + 6052864);     // 50,577,408 (3 planes)
  unsigned short* xg    = (unsigned short*)(wsb + 56630272);    // 16,859,136
  unsigned short* attno = (unsigned short*)(wsb + 73489408);    // 16,859,136
  unsigned short* wts   = (unsigned short*)(wsb + 90348544);    //  3,538,944
  float*          projt = (float*)(wsb + 93887488);             // 33,718,272
  float*          x1    = (float*)(wsb + 127605760);            // 33,718,272
  unsigned short* x1b   = (unsigned short*)(wsb + 161324032);   // 16,859,136
  unsigned short* hbuf  = qkvp;   // overlays qkv+xg (67.4MB), dead after attn
  float*          h2    = projt;  // dead after LN1

  unsigned short* wq  = wts;
  unsigned short* wpj = wts + 442368;
  unsigned short* wf1 = wts + 589824;
  unsigned short* wf2 = wts + 1179648;

  cvt_bf16_kernel<<<216, 256, 0, stream>>>(qkv_w, wq, 55296);
  cvt_bf16_kernel<<<72,  256, 0, stream>>>(proj_w, wpj, 18432);
  cvt_bf16_kernel<<<288, 256, 0, stream>>>(fc1_w, wf1, 73728);
  cvt_bf16_kernel<<<288, 256, 0, stream>>>(fc2_w, wf2, 73728);
  gather_x_kernel<<<4116, 256, 0, stream>>>(x, xg);
  cpb_table_kernel<<<103, 256, 0, stream>>>(cpb_w1, cpb_b1, cpb_w2, tbl);
  cpb_bias_frag_kernel<<<1452, 256, 0, stream>>>(tbl, biasf);

  // qkv: [21952,384] @ [1152,384]^T -> q/k/v planes bf16
  gemm_bf16<0><<<dim3(9, 343), 256, 0, stream>>>(xg, wq, q_bias, v_bias, qkvp, 384, 1152);

  attn_mfma<<<768, 512, 0, stream>>>(qkvp, qkvp + kPlaneE, qkvp + 2 * kPlaneE,
                                     biasf, lscale, attno);

  // proj: [21952,384] @ [384,384]^T + b -> fp32
  gemm_bf16<1><<<dim3(3, 343), 256, 0, stream>>>(attno, wpj, proj_b, nullptr, projt, 384, 384);

  // x1 = x + LN(win_rev(proj)); also write bf16 copy
  ln_kernel<1, 1><<<21952, 64, 0, stream>>>(projt, x, n1g, n1b, x1, x1b);

  // fc1 + gelu: [21952,384] @ [1536,384]^T -> bf16
  gemm_bf16<2><<<dim3(12, 343), 256, 0, stream>>>(x1b, wf1, fc1_b, nullptr, hbuf, 384, 1536);

  // fc2: [21952,1536] @ [384,1536]^T -> fp32
  gemm_bf16<1><<<dim3(3, 343), 256, 0, stream>>>(hbuf, wf2, fc2_b, nullptr, h2, 1536, 384);

  // out = x1 + LN(h2)
  ln_kernel<0, 0><<<21952, 64, 0, stream>>>(h2, x1, n2g, n2b, outp, nullptr);
}